// Round 4
// baseline (159.829 us; speedup 1.0000x reference)
//
#include <hip/hip_runtime.h>

#define NB 16
#define NC 7
#define NK 6
#define HC 160
#define WC 160
#define HF 640
#define WF 640
#define NCOARSE (HC*WC)             // 25600 coarse pixels per batch
#define NFINE   (HF*WF)             // 409600 fine pixels per batch
#define BLOCKS_PER_B (NCOARSE/256)  // 100
#define NACC 27
#define ACC_STRIDE 32
#define EPSF 1e-6f

// ---------------- ws layout (bytes) ----------------
// acc      float[16*32]   @ 0      (2048)   [zeroed by init]
// thrkeys  uint[16]       @ 2048            [written by B]
// flb      int[16]        @ 2112            [written by B]
// bits     uint[409600]   @ 4096            [written by A]
#define WS_THR   2048
#define WS_FLB   2112
#define WS_BITS  4096

__device__ __forceinline__ unsigned score_key(float s) {
    unsigned u = __float_as_uint(s);
    return (u & 0x80000000u) ? ~u : (u | 0x80000000u);
}

// ---------- init: zero the 27-sum accumulators ----------
__global__ __launch_bounds__(256) void psel_init(uint4* __restrict__ ws4) {
    int i = threadIdx.x;
    if (i < 2048/16) ws4[i] = uint4{0u, 0u, 0u, 0u};
}

// ---------- Phase A: bit-pack g/m per coarse pixel ----------
__global__ __launch_bounds__(256) void psel_phaseA(
    const float* __restrict__ gt, const float* __restrict__ tm,
    unsigned* __restrict__ bitsbuf)
{
    int bid = blockIdx.x;
    int b = bid / BLOCKS_PER_B;
    int r = (bid % BLOCKS_PER_B) * 256 + threadIdx.x;
    int cy = r / WC, cx = r % WC;
    const float* gtb = gt + (size_t)b * NFINE;
    const float* tmb = tm + (size_t)b * NFINE;
    unsigned gb = 0, mb = 0;
    #pragma unroll
    for (int row = 0; row < 4; ++row) {
        int off = (cy*4 + row)*WF + cx*4;
        float4 g4 = *reinterpret_cast<const float4*>(gtb + off);
        float4 m4 = *reinterpret_cast<const float4*>(tmb + off);
        unsigned sh = 4*row;
        gb |= ((g4.x > 0.5f) ? 1u : 0u) << (sh+0);
        gb |= ((g4.y > 0.5f) ? 1u : 0u) << (sh+1);
        gb |= ((g4.z > 0.5f) ? 1u : 0u) << (sh+2);
        gb |= ((g4.w > 0.5f) ? 1u : 0u) << (sh+3);
        mb |= ((m4.x > 0.5f) ? 1u : 0u) << (sh+0);
        mb |= ((m4.y > 0.5f) ? 1u : 0u) << (sh+1);
        mb |= ((m4.z > 0.5f) ? 1u : 0u) << (sh+2);
        mb |= ((m4.w > 0.5f) ? 1u : 0u) << (sh+3);
    }
    bitsbuf[b*NCOARSE + r] = (mb << 16) | gb;
}

// Weighted descending select over an LDS histogram, parallel suffix-scan.
// Finds bin v = first (from top) where cumulative weight >= k; krem relative
// to weight strictly above v. Returns via res[0]=bin, res[1]=krem.
template<int NBINS>
__device__ __forceinline__ void lds_select(int* __restrict__ lh, int* __restrict__ cs,
                                           int* __restrict__ res, int k,
                                           int& bin, int& krem)
{
    constexpr int CH = NBINS / 256;
    int t = threadIdx.x;
    __syncthreads();
    int s = 0;
    #pragma unroll
    for (int j = 0; j < CH; ++j) s += lh[t*CH + j];
    cs[t] = s;
    __syncthreads();
    #pragma unroll
    for (int off = 1; off < 256; off <<= 1) {
        int v = cs[t] + ((t + off < 256) ? cs[t + off] : 0);
        __syncthreads();
        cs[t] = v;
        __syncthreads();
    }
    if (t == 0) { res[0] = 0; res[1] = k; }   // guard (unreachable when k<=total)
    __syncthreads();
    int St = cs[t];
    int Snext = (t < 255) ? cs[t+1] : 0;
    if (St >= k && Snext < k) {
        int cum = Snext;
        for (int u = t*CH + CH - 1; u >= t*CH; --u) {
            cum += lh[u];
            if (cum >= k) { res[0] = u; res[1] = k - (cum - lh[u]); break; }
        }
    }
    __syncthreads();
    bin = res[0]; krem = res[1];
    __syncthreads();   // safe to reuse lh/cs after this
}

// ---------- Phase B: full OHEM threshold select, one block per batch ----------
__global__ __launch_bounds__(256) void psel_phaseB(
    const float* __restrict__ maps, const unsigned* __restrict__ bitsbuf,
    unsigned* __restrict__ thrkeys, int* __restrict__ flb)
{
    __shared__ int lh[2048];
    __shared__ int cs[256];
    __shared__ int res[2];
    __shared__ int sp[4], sn[4];
    int b = blockIdx.x;
    int t = threadIdx.x;
    const float* mp = maps + (size_t)b * NC * NCOARSE;   // channel 0
    const unsigned* bb = bitsbuf + b * NCOARSE;

    // pass 0: pos / neg_total counts
    int pos = 0, neg = 0;
    for (int i = t; i < NCOARSE; i += 256) {
        unsigned w = bb[i];
        pos += __popc(w & (w >> 16) & 0xFFFFu);
        neg += 16 - __popc(w & 0xFFFFu);
    }
    #pragma unroll
    for (int off = 32; off; off >>= 1) {
        pos += __shfl_down(pos, off);
        neg += __shfl_down(neg, off);
    }
    int wid = t >> 6, lane = t & 63;
    if (lane == 0) { sp[wid] = pos; sn[wid] = neg; }
    __syncthreads();
    pos = sp[0] + sp[1] + sp[2] + sp[3];
    neg = sn[0] + sn[1] + sn[2] + sn[3];
    int k = pos * 3; if (k > neg) k = neg;
    if (pos == 0 || k == 0) {
        if (t == 0) { thrkeys[b] = 0u; flb[b] = 1; }
        return;
    }

    // pass 1: top 11 bits
    for (int j = t; j < 2048; j += 256) lh[j] = 0;
    __syncthreads();
    for (int i = t; i < NCOARSE; i += 256) {
        int wt = 16 - __popc(bb[i] & 0xFFFFu);
        if (wt) {
            unsigned key = score_key(mp[i]);
            atomicAdd(&lh[key >> 21], wt);
        }
    }
    int v;
    lds_select<2048>(lh, cs, res, k, v, k);
    unsigned prefix = (unsigned)v;

    // pass 2: middle 11 bits
    for (int j = t; j < 2048; j += 256) lh[j] = 0;
    __syncthreads();
    for (int i = t; i < NCOARSE; i += 256) {
        int wt = 16 - __popc(bb[i] & 0xFFFFu);
        if (wt) {
            unsigned key = score_key(mp[i]);
            if ((key >> 21) == prefix) atomicAdd(&lh[(key >> 10) & 2047u], wt);
        }
    }
    lds_select<2048>(lh, cs, res, k, v, k);
    prefix = (prefix << 11) | (unsigned)v;

    // pass 3: low 10 bits
    for (int j = t; j < 1024; j += 256) lh[j] = 0;
    __syncthreads();
    for (int i = t; i < NCOARSE; i += 256) {
        int wt = 16 - __popc(bb[i] & 0xFFFFu);
        if (wt) {
            unsigned key = score_key(mp[i]);
            if ((key >> 10) == prefix) atomicAdd(&lh[key & 1023u], wt);
        }
    }
    lds_select<1024>(lh, cs, res, k, v, k);
    if (t == 0) { thrkeys[b] = (prefix << 10) | (unsigned)v; flb[b] = 0; }
}

// ---------- Phase C2: threshold-dependent part of B_t (tiny) ----------
__global__ __launch_bounds__(256) void psel_phaseC2(
    const float* __restrict__ maps, const unsigned* __restrict__ bitsbuf,
    const unsigned* __restrict__ thrkeys, const int* __restrict__ flb,
    float* __restrict__ acc)
{
    int bid = blockIdx.x;
    int b = bid / 25;
    int q = (bid % 25) * 256 + threadIdx.x;   // float4 index into channel 0
    const float4 m4 = reinterpret_cast<const float4*>(maps + (size_t)b * NC * NCOARSE)[q];
    const uint4  b4 = reinterpret_cast<const uint4*>(bitsbuf + b * NCOARSE)[q];
    int fb = flb[b];
    unsigned tk = thrkeys[b];
    float ssum = 0.f;
    float mv[4] = {m4.x, m4.y, m4.z, m4.w};
    unsigned wv[4] = {b4.x, b4.y, b4.z, b4.w};
    #pragma unroll
    for (int j = 0; j < 4; ++j) {
        unsigned w = wv[j];
        float cm  = (float)__popc(w >> 16);
        float cgm = (float)__popc(w & (w >> 16) & 0xFFFFu);
        if (fb || score_key(mv[j]) >= tk) {
            float s = 1.0f / (1.0f + expf(-mv[j]));
            ssum += s * s * (cm - cgm);
        }
    }
    #pragma unroll
    for (int off = 32; off; off >>= 1) ssum += __shfl_down(ssum, off);
    __shared__ float sr[4];
    int wid = threadIdx.x >> 6, lane = threadIdx.x & 63;
    if (lane == 0) sr[wid] = ssum;
    __syncthreads();
    if (threadIdx.x == 0)
        atomicAdd(&acc[b*ACC_STRIDE + 1], sr[0] + sr[1] + sr[2] + sr[3]);
}

// ---------- Phase C: main fused reduction (threshold-independent) ----------
__global__ __launch_bounds__(256) void psel_phaseC(
    const float* __restrict__ maps, const float* __restrict__ gk,
    const unsigned* __restrict__ bitsbuf, float* __restrict__ acc)
{
    int bid = blockIdx.x;
    int b = bid / BLOCKS_PER_B;
    int r = (bid % BLOCKS_PER_B) * 256 + threadIdx.x;
    int cy = r / WC, cx = r % WC;

    float sig[NC]; float mv0 = 0.f, mv6 = 0.f;
    #pragma unroll
    for (int c = 0; c < NC; ++c) {
        float mv = maps[((size_t)(b*NC + c))*NCOARSE + r];
        if (c == 0) mv0 = mv;
        if (c == 6) mv6 = mv;
        sig[c] = 1.0f / (1.0f + expf(-mv));
    }
    bool at = mv0 > 0.0f;
    bool a5 = mv6 > 0.0f;

    unsigned bits = bitsbuf[b*NCOARSE + r];
    unsigned mbits = bits >> 16, gbits = bits & 0xFFFFu;
    unsigned gmb = mbits & gbits;
    float cm  = (float)__popc(mbits);
    float cgm = (float)__popc(gmb);

    float cgkm[NK];
    float cg5mg = 0.f;
    #pragma unroll
    for (int k = 0; k < NK; ++k) {               // k-outer: 4 coherent row streams
        const float* gkb = gk + (size_t)(b*NK + k) * NFINE + (cy*4)*WF + cx*4;
        float s = 0.f, s5 = 0.f;
        #pragma unroll
        for (int row = 0; row < 4; ++row) {
            float4 k4 = *reinterpret_cast<const float4*>(gkb + row*WF);
            unsigned mrow = (mbits >> (4*row)) & 15u;
            unsigned grow = (gmb   >> (4*row)) & 15u;
            if (mrow & 1u) s += k4.x;
            if (mrow & 2u) s += k4.y;
            if (mrow & 4u) s += k4.z;
            if (mrow & 8u) s += k4.w;
            if (k == NK-1) {
                if (grow & 1u) s5 += k4.x;
                if (grow & 2u) s5 += k4.y;
                if (grow & 4u) s5 += k4.z;
                if (grow & 8u) s5 += k4.w;
            }
        }
        cgkm[k] = s;
        if (k == NK-1) cg5mg = s5;
    }

    float vals[NACC];
    float s0 = sig[0];
    vals[0] = s0 * cgm;                          // A_t
    vals[1] = s0 * s0 * cgm;                     // B_t threshold-indep part (C2 adds rest)
    vals[2] = cgm;                               // C_t
    vals[3] = cm;                                // S_cm
    vals[4] = at ? cgm : 0.f;                    // n11 text
    vals[5] = at ? cm  : 0.f;
    #pragma unroll
    for (int k = 0; k < NK; ++k) {
        float sk = sig[k+1];
        vals[6 + 3*k] = at ? sk * cgkm[k] : 0.f;       // A_k
        vals[7 + 3*k] = at ? sk * sk * cm : 0.f;       // B_k
        vals[8 + 3*k] = at ? cgkm[k] : 0.f;            // C_k
    }
    vals[24] = a5 ? cg5mg : 0.f;                 // m11 kernel-iou
    vals[25] = a5 ? cgm   : 0.f;
    vals[26] = cg5mg;

    #pragma unroll
    for (int i = 0; i < NACC; ++i) {
        #pragma unroll
        for (int off = 32; off; off >>= 1)
            vals[i] += __shfl_down(vals[i], off);
    }
    __shared__ float red[4][NACC];
    int wid = threadIdx.x >> 6, lane = threadIdx.x & 63;
    if (lane == 0) {
        #pragma unroll
        for (int i = 0; i < NACC; ++i) red[wid][i] = vals[i];
    }
    __syncthreads();
    if (threadIdx.x < NACC) {
        float s = red[0][threadIdx.x] + red[1][threadIdx.x]
                + red[2][threadIdx.x] + red[3][threadIdx.x];
        atomicAdd(&acc[b*ACC_STRIDE + threadIdx.x], s);
    }
}

// ---------- Phase D: final per-batch algebra + output sums ----------
__global__ __launch_bounds__(64) void psel_phaseD(
    const float* __restrict__ acc, float* __restrict__ out)
{
    int b = threadIdx.x;
    float l = 0.f, lt = 0.f, lk = 0.f, it = 0.f, ik = 0.f;
    if (b < NB) {
        const float* a = acc + b*ACC_STRIDE;
        float At = a[0], Bt = a[1], Ct = a[2], Sm = a[3], Satgm = a[4], Satm = a[5];
        lt = 1.f - 2.f*At / (Bt + Ct + 2.f*EPSF);
        float n11 = Satgm;
        float u1 = Satm + Ct - Satgm;
        float i0 = Sm - u1;
        float u0 = Sm - n11;
        it = 0.5f * (i0/(u0 + EPSF) + n11/(u1 + EPSF));
        float lks = 0.f;
        #pragma unroll
        for (int k = 0; k < NK; ++k) {
            float Ak = a[6+3*k], Bk = a[7+3*k], Ck = a[8+3*k];
            lks += 1.f - 2.f*Ak / (Bk + Ck + 2.f*EPSF);
        }
        lk = lks / (float)NK;
        float m11 = a[24], Sa5gm = a[25], Sg5 = a[26];
        float ku1 = Sa5gm + Sg5 - m11;
        float ki0 = Ct - ku1;
        float ku0 = Ct - m11;
        ik = 0.5f * (ki0/(ku0 + EPSF) + m11/(ku1 + EPSF));
        l = 0.7f*lt + 0.3f*lk;
    }
    #pragma unroll
    for (int off = 8; off; off >>= 1) {
        l  += __shfl_down(l,  off);
        lt += __shfl_down(lt, off);
        lk += __shfl_down(lk, off);
        it += __shfl_down(it, off);
        ik += __shfl_down(ik, off);
    }
    if (threadIdx.x == 0) {
        out[0] = l; out[1] = lt; out[2] = lk; out[3] = it; out[4] = ik;
    }
}

extern "C" void kernel_launch(void* const* d_in, const int* in_sizes, int n_in,
                              void* d_out, int out_size, void* d_ws, size_t ws_size,
                              hipStream_t stream) {
    const float* maps = (const float*)d_in[0];
    const float* gt   = (const float*)d_in[1];
    const float* gk   = (const float*)d_in[2];
    const float* tm   = (const float*)d_in[3];
    float* out = (float*)d_out;
    char* ws = (char*)d_ws;
    float*    acc     = (float*)ws;
    unsigned* thrkeys = (unsigned*)(ws + WS_THR);
    int*      flb     = (int*)(ws + WS_FLB);
    unsigned* bits    = (unsigned*)(ws + WS_BITS);

    psel_init   <<<1, 256, 0, stream>>>((uint4*)ws);
    psel_phaseA <<<NB*BLOCKS_PER_B, 256, 0, stream>>>(gt, tm, bits);
    psel_phaseB <<<NB, 256, 0, stream>>>(maps, bits, thrkeys, flb);
    psel_phaseC2<<<NB*25, 256, 0, stream>>>(maps, bits, thrkeys, flb, acc);
    psel_phaseC <<<NB*BLOCKS_PER_B, 256, 0, stream>>>(maps, gk, bits, acc);
    psel_phaseD <<<1, 64, 0, stream>>>(acc, out);
}

// Round 5
// 68.415 us; speedup vs baseline: 2.3362x; 2.3362x over previous
//
#include <hip/hip_runtime.h>

#define NB 16
#define NC 7
#define NK 6
#define HC 160
#define WC 160
#define HF 640
#define WF 640
#define NCOARSE (HC*WC)             // 25600 coarse pixels per batch
#define NFINE   (HF*WF)             // 409600 fine pixels per batch
#define BLOCKS_PER_B (NCOARSE/256)  // 100
#define NQ4 (NCOARSE/4)             // 6400 float4/uint4 per batch
#define NACC 27
#define ACC_STRIDE 32
#define EPSF 1e-6f

// ---------------- ws layout (bytes) ----------------
// acc      float[16*32]   @ 0      (2048)   [zeroed by init]
// thrkeys  uint[16]       @ 2048            [written by B]
// flb      int[16]        @ 2112            [written by B]
// bits     uint[409600]   @ 4096            [written by A]
#define WS_THR   2048
#define WS_FLB   2112
#define WS_BITS  4096

__device__ __forceinline__ unsigned score_key(float s) {
    unsigned u = __float_as_uint(s);
    return (u & 0x80000000u) ? ~u : (u | 0x80000000u);
}

// ---------- init: zero the 27-sum accumulators ----------
__global__ __launch_bounds__(256) void psel_init(uint4* __restrict__ ws4) {
    int i = threadIdx.x;
    if (i < 2048/16) ws4[i] = uint4{0u, 0u, 0u, 0u};
}

// ---------- Phase A: bit-pack g/m per coarse pixel ----------
__global__ __launch_bounds__(256) void psel_phaseA(
    const float* __restrict__ gt, const float* __restrict__ tm,
    unsigned* __restrict__ bitsbuf)
{
    int bid = blockIdx.x;
    int b = bid / BLOCKS_PER_B;
    int r = (bid % BLOCKS_PER_B) * 256 + threadIdx.x;
    int cy = r / WC, cx = r % WC;
    const float* gtb = gt + (size_t)b * NFINE;
    const float* tmb = tm + (size_t)b * NFINE;
    unsigned gb = 0, mb = 0;
    #pragma unroll
    for (int row = 0; row < 4; ++row) {
        int off = (cy*4 + row)*WF + cx*4;
        float4 g4 = *reinterpret_cast<const float4*>(gtb + off);
        float4 m4 = *reinterpret_cast<const float4*>(tmb + off);
        unsigned sh = 4*row;
        gb |= ((g4.x > 0.5f) ? 1u : 0u) << (sh+0);
        gb |= ((g4.y > 0.5f) ? 1u : 0u) << (sh+1);
        gb |= ((g4.z > 0.5f) ? 1u : 0u) << (sh+2);
        gb |= ((g4.w > 0.5f) ? 1u : 0u) << (sh+3);
        mb |= ((m4.x > 0.5f) ? 1u : 0u) << (sh+0);
        mb |= ((m4.y > 0.5f) ? 1u : 0u) << (sh+1);
        mb |= ((m4.z > 0.5f) ? 1u : 0u) << (sh+2);
        mb |= ((m4.w > 0.5f) ? 1u : 0u) << (sh+3);
    }
    bitsbuf[b*NCOARSE + r] = (mb << 16) | gb;
}

// Block-wide (1024 thr) weighted descending select over LDS histogram.
// Hierarchical suffix scan: per-wave shfl suffix + 16 wave totals.
// Returns bin; krem updated to k relative to weight strictly above bin.
template<int NBINS>
__device__ __forceinline__ int bsel(int* __restrict__ lh, int* __restrict__ ws16,
                                    int* __restrict__ wsuf, int* __restrict__ res,
                                    int k, int& krem)
{
    constexpr int CH = NBINS / 1024;
    int t = threadIdx.x, wid = t >> 6, lane = t & 63;
    __syncthreads();                 // histogram atomics complete
    int c = 0;
    #pragma unroll
    for (int j = 0; j < CH; ++j) c += lh[t*CH + j];
    int s = c;                       // suffix sum within wave (from lane upward)
    #pragma unroll
    for (int off = 1; off < 64; off <<= 1) {
        int v = __shfl_down(s, off);
        if (lane + off < 64) s += v;
    }
    if (lane == 0) ws16[wid] = s;    // wave total
    __syncthreads();
    if (t < 16) {
        int sum = 0;
        for (int j = t; j < 16; ++j) sum += ws16[j];
        wsuf[t] = sum;
    }
    if (t == 0) { wsuf[16] = 0; res[0] = 0; res[1] = k; }
    __syncthreads();
    int G = s + wsuf[wid + 1];       // suffix sum from this thread's chunk to top
    int above = G - c;
    if (G >= k && above < k) {       // exactly one straddling thread
        int cum = above;
        for (int u = t*CH + CH - 1; u >= t*CH; --u) {
            cum += lh[u];
            if (cum >= k) { res[0] = u; res[1] = k - (cum - lh[u]); break; }
        }
    }
    __syncthreads();
    int bin = res[0]; krem = res[1];
    __syncthreads();                 // lh safe to reuse
    return bin;
}

// ---------- Phase B: full OHEM threshold select, one 1024-thread block per batch ----------
__global__ __launch_bounds__(1024) void psel_phaseB(
    const float* __restrict__ maps, const unsigned* __restrict__ bitsbuf,
    unsigned* __restrict__ thrkeys, int* __restrict__ flb)
{
    __shared__ unsigned wpack[NQ4];  // 4 packed 8-bit weights per uint (25.6 KB)
    __shared__ int lh[2048];
    __shared__ int sp[16], sn[16];
    __shared__ int ws16[16], wsuf[17], res[2];
    int b = blockIdx.x;
    int t = threadIdx.x;
    int wid = t >> 6, lane = t & 63;
    const float4* mp4 = reinterpret_cast<const float4*>(maps + (size_t)b * NC * NCOARSE);
    const uint4*  bb4 = reinterpret_cast<const uint4*>(bitsbuf + (size_t)b * NCOARSE);

    // ---- pass 1: build weight cache + top-11-bit histogram + pos/neg counts ----
    for (int j = t; j < 2048; j += 1024) lh[j] = 0;
    __syncthreads();
    int pos = 0, negt = 0;
    for (int i4 = t; i4 < NQ4; i4 += 1024) {
        float4 m4 = mp4[i4];
        uint4  b4 = bb4[i4];
        float    mv[4] = {m4.x, m4.y, m4.z, m4.w};
        unsigned bv[4] = {b4.x, b4.y, b4.z, b4.w};
        unsigned pk = 0;
        #pragma unroll
        for (int j = 0; j < 4; ++j) {
            unsigned g = bv[j] & 0xFFFFu, m = bv[j] >> 16;
            pos += __popc(g & m);
            int w = 16 - __popc(g);
            negt += w;
            pk |= (unsigned)w << (8*j);
            if (w) atomicAdd(&lh[score_key(mv[j]) >> 21], w);
        }
        wpack[i4] = pk;
    }
    #pragma unroll
    for (int off = 32; off; off >>= 1) {
        pos  += __shfl_down(pos,  off);
        negt += __shfl_down(negt, off);
    }
    if (lane == 0) { sp[wid] = pos; sn[wid] = negt; }
    __syncthreads();
    if (t == 0) {
        int P = 0, N = 0;
        for (int j = 0; j < 16; ++j) { P += sp[j]; N += sn[j]; }
        int k = P * 3; if (k > N) k = N;
        res[1] = (P == 0 || k == 0) ? -1 : k;
    }
    __syncthreads();
    int k = res[1];
    if (k < 0) {
        if (t == 0) { thrkeys[b] = 0u; flb[b] = 1; }
        return;
    }
    int v = bsel<2048>(lh, ws16, wsuf, res, k, k);
    unsigned prefix = (unsigned)v;

    // ---- pass 2: middle 11 bits ----
    for (int j = t; j < 2048; j += 1024) lh[j] = 0;
    __syncthreads();
    for (int i4 = t; i4 < NQ4; i4 += 1024) {
        float4 m4 = mp4[i4];
        unsigned pk = wpack[i4];
        float mv[4] = {m4.x, m4.y, m4.z, m4.w};
        #pragma unroll
        for (int j = 0; j < 4; ++j) {
            int w = (pk >> (8*j)) & 255;
            if (w) {
                unsigned key = score_key(mv[j]);
                if ((key >> 21) == prefix) atomicAdd(&lh[(key >> 10) & 2047u], w);
            }
        }
    }
    v = bsel<2048>(lh, ws16, wsuf, res, k, k);
    prefix = (prefix << 11) | (unsigned)v;

    // ---- pass 3: low 10 bits ----
    for (int j = t; j < 1024; j += 1024) lh[j] = 0;
    __syncthreads();
    for (int i4 = t; i4 < NQ4; i4 += 1024) {
        float4 m4 = mp4[i4];
        unsigned pk = wpack[i4];
        float mv[4] = {m4.x, m4.y, m4.z, m4.w};
        #pragma unroll
        for (int j = 0; j < 4; ++j) {
            int w = (pk >> (8*j)) & 255;
            if (w) {
                unsigned key = score_key(mv[j]);
                if ((key >> 10) == prefix) atomicAdd(&lh[key & 1023u], w);
            }
        }
    }
    v = bsel<1024>(lh, ws16, wsuf, res, k, k);
    if (t == 0) { thrkeys[b] = (prefix << 10) | (unsigned)v; flb[b] = 0; }
}

// ---------- Phase C2: threshold-dependent part of B_t (tiny) ----------
__global__ __launch_bounds__(256) void psel_phaseC2(
    const float* __restrict__ maps, const unsigned* __restrict__ bitsbuf,
    const unsigned* __restrict__ thrkeys, const int* __restrict__ flb,
    float* __restrict__ acc)
{
    int bid = blockIdx.x;
    int b = bid / 25;
    int q = (bid % 25) * 256 + threadIdx.x;   // float4 index into channel 0
    const float4 m4 = reinterpret_cast<const float4*>(maps + (size_t)b * NC * NCOARSE)[q];
    const uint4  b4 = reinterpret_cast<const uint4*>(bitsbuf + b * NCOARSE)[q];
    int fb = flb[b];
    unsigned tk = thrkeys[b];
    float ssum = 0.f;
    float mv[4] = {m4.x, m4.y, m4.z, m4.w};
    unsigned wv[4] = {b4.x, b4.y, b4.z, b4.w};
    #pragma unroll
    for (int j = 0; j < 4; ++j) {
        unsigned w = wv[j];
        float cm  = (float)__popc(w >> 16);
        float cgm = (float)__popc(w & (w >> 16) & 0xFFFFu);
        if (fb || score_key(mv[j]) >= tk) {
            float s = 1.0f / (1.0f + expf(-mv[j]));
            ssum += s * s * (cm - cgm);
        }
    }
    #pragma unroll
    for (int off = 32; off; off >>= 1) ssum += __shfl_down(ssum, off);
    __shared__ float sr[4];
    int wid = threadIdx.x >> 6, lane = threadIdx.x & 63;
    if (lane == 0) sr[wid] = ssum;
    __syncthreads();
    if (threadIdx.x == 0)
        atomicAdd(&acc[b*ACC_STRIDE + 1], sr[0] + sr[1] + sr[2] + sr[3]);
}

// ---------- Phase C: main fused reduction (threshold-independent) ----------
__global__ __launch_bounds__(256) void psel_phaseC(
    const float* __restrict__ maps, const float* __restrict__ gk,
    const unsigned* __restrict__ bitsbuf, float* __restrict__ acc)
{
    int bid = blockIdx.x;
    int b = bid / BLOCKS_PER_B;
    int r = (bid % BLOCKS_PER_B) * 256 + threadIdx.x;
    int cy = r / WC, cx = r % WC;

    float sig[NC]; float mv0 = 0.f, mv6 = 0.f;
    #pragma unroll
    for (int c = 0; c < NC; ++c) {
        float mv = maps[((size_t)(b*NC + c))*NCOARSE + r];
        if (c == 0) mv0 = mv;
        if (c == 6) mv6 = mv;
        sig[c] = 1.0f / (1.0f + expf(-mv));
    }
    bool at = mv0 > 0.0f;
    bool a5 = mv6 > 0.0f;

    unsigned bits = bitsbuf[b*NCOARSE + r];
    unsigned mbits = bits >> 16, gbits = bits & 0xFFFFu;
    unsigned gmb = mbits & gbits;
    float cm  = (float)__popc(mbits);
    float cgm = (float)__popc(gmb);

    float cgkm[NK];
    float cg5mg = 0.f;
    #pragma unroll
    for (int k = 0; k < NK; ++k) {               // k-outer: 4 coherent row streams
        const float* gkb = gk + (size_t)(b*NK + k) * NFINE + (cy*4)*WF + cx*4;
        float s = 0.f, s5 = 0.f;
        #pragma unroll
        for (int row = 0; row < 4; ++row) {
            float4 k4 = *reinterpret_cast<const float4*>(gkb + row*WF);
            unsigned mrow = (mbits >> (4*row)) & 15u;
            unsigned grow = (gmb   >> (4*row)) & 15u;
            if (mrow & 1u) s += k4.x;
            if (mrow & 2u) s += k4.y;
            if (mrow & 4u) s += k4.z;
            if (mrow & 8u) s += k4.w;
            if (k == NK-1) {
                if (grow & 1u) s5 += k4.x;
                if (grow & 2u) s5 += k4.y;
                if (grow & 4u) s5 += k4.z;
                if (grow & 8u) s5 += k4.w;
            }
        }
        cgkm[k] = s;
        if (k == NK-1) cg5mg = s5;
    }

    float vals[NACC];
    float s0 = sig[0];
    vals[0] = s0 * cgm;                          // A_t
    vals[1] = s0 * s0 * cgm;                     // B_t threshold-indep part (C2 adds rest)
    vals[2] = cgm;                               // C_t
    vals[3] = cm;                                // S_cm
    vals[4] = at ? cgm : 0.f;                    // n11 text
    vals[5] = at ? cm  : 0.f;
    #pragma unroll
    for (int k = 0; k < NK; ++k) {
        float sk = sig[k+1];
        vals[6 + 3*k] = at ? sk * cgkm[k] : 0.f;       // A_k
        vals[7 + 3*k] = at ? sk * sk * cm : 0.f;       // B_k
        vals[8 + 3*k] = at ? cgkm[k] : 0.f;            // C_k
    }
    vals[24] = a5 ? cg5mg : 0.f;                 // m11 kernel-iou
    vals[25] = a5 ? cgm   : 0.f;
    vals[26] = cg5mg;

    #pragma unroll
    for (int i = 0; i < NACC; ++i) {
        #pragma unroll
        for (int off = 32; off; off >>= 1)
            vals[i] += __shfl_down(vals[i], off);
    }
    __shared__ float red[4][NACC];
    int wid = threadIdx.x >> 6, lane = threadIdx.x & 63;
    if (lane == 0) {
        #pragma unroll
        for (int i = 0; i < NACC; ++i) red[wid][i] = vals[i];
    }
    __syncthreads();
    if (threadIdx.x < NACC) {
        float s = red[0][threadIdx.x] + red[1][threadIdx.x]
                + red[2][threadIdx.x] + red[3][threadIdx.x];
        atomicAdd(&acc[b*ACC_STRIDE + threadIdx.x], s);
    }
}

// ---------- Phase D: final per-batch algebra + output sums ----------
__global__ __launch_bounds__(64) void psel_phaseD(
    const float* __restrict__ acc, float* __restrict__ out)
{
    int b = threadIdx.x;
    float l = 0.f, lt = 0.f, lk = 0.f, it = 0.f, ik = 0.f;
    if (b < NB) {
        const float* a = acc + b*ACC_STRIDE;
        float At = a[0], Bt = a[1], Ct = a[2], Sm = a[3], Satgm = a[4], Satm = a[5];
        lt = 1.f - 2.f*At / (Bt + Ct + 2.f*EPSF);
        float n11 = Satgm;
        float u1 = Satm + Ct - Satgm;
        float i0 = Sm - u1;
        float u0 = Sm - n11;
        it = 0.5f * (i0/(u0 + EPSF) + n11/(u1 + EPSF));
        float lks = 0.f;
        #pragma unroll
        for (int k = 0; k < NK; ++k) {
            float Ak = a[6+3*k], Bk = a[7+3*k], Ck = a[8+3*k];
            lks += 1.f - 2.f*Ak / (Bk + Ck + 2.f*EPSF);
        }
        lk = lks / (float)NK;
        float m11 = a[24], Sa5gm = a[25], Sg5 = a[26];
        float ku1 = Sa5gm + Sg5 - m11;
        float ki0 = Ct - ku1;
        float ku0 = Ct - m11;
        ik = 0.5f * (ki0/(ku0 + EPSF) + m11/(ku1 + EPSF));
        l = 0.7f*lt + 0.3f*lk;
    }
    #pragma unroll
    for (int off = 8; off; off >>= 1) {
        l  += __shfl_down(l,  off);
        lt += __shfl_down(lt, off);
        lk += __shfl_down(lk, off);
        it += __shfl_down(it, off);
        ik += __shfl_down(ik, off);
    }
    if (threadIdx.x == 0) {
        out[0] = l; out[1] = lt; out[2] = lk; out[3] = it; out[4] = ik;
    }
}

extern "C" void kernel_launch(void* const* d_in, const int* in_sizes, int n_in,
                              void* d_out, int out_size, void* d_ws, size_t ws_size,
                              hipStream_t stream) {
    const float* maps = (const float*)d_in[0];
    const float* gt   = (const float*)d_in[1];
    const float* gk   = (const float*)d_in[2];
    const float* tm   = (const float*)d_in[3];
    float* out = (float*)d_out;
    char* ws = (char*)d_ws;
    float*    acc     = (float*)ws;
    unsigned* thrkeys = (unsigned*)(ws + WS_THR);
    int*      flb     = (int*)(ws + WS_FLB);
    unsigned* bits    = (unsigned*)(ws + WS_BITS);

    psel_init   <<<1, 256, 0, stream>>>((uint4*)ws);
    psel_phaseA <<<NB*BLOCKS_PER_B, 256, 0, stream>>>(gt, tm, bits);
    psel_phaseB <<<NB, 1024, 0, stream>>>(maps, bits, thrkeys, flb);
    psel_phaseC2<<<NB*25, 256, 0, stream>>>(maps, bits, thrkeys, flb, acc);
    psel_phaseC <<<NB*BLOCKS_PER_B, 256, 0, stream>>>(maps, gk, bits, acc);
    psel_phaseD <<<1, 64, 0, stream>>>(acc, out);
}